// Round 2
// baseline (638.958 us; speedup 1.0000x reference)
//
#include <hip/hip_runtime.h>
#include <hip/hip_bf16.h>

#define NB 32768
#define DIN 512
#define DHID 4096
#define DOUT 512

typedef __attribute__((ext_vector_type(8))) __bf16 bf16x8;
typedef __attribute__((ext_vector_type(4))) float f32x4;

__device__ __forceinline__ unsigned short f2bf(float f) {
  unsigned u = __builtin_bit_cast(unsigned, f);
  u += 0x7FFFu + ((u >> 16) & 1u);
  return (unsigned short)(u >> 16);
}

__device__ __forceinline__ void gload16(void* lds, const void* g) {
  __builtin_amdgcn_global_load_lds(
      (const __attribute__((address_space(1))) void*)g,
      (__attribute__((address_space(3))) void*)lds, 16, 0, 0);
}

// ---------------- prep: xn = bf16((x - mean)/std) ----------------
__global__ __launch_bounds__(256) void k_prep_x(
    const float4* __restrict__ x, const float* __restrict__ mean,
    const float* __restrict__ stdv, ushort4* __restrict__ xn) {
  const int i = blockIdx.x * 256 + threadIdx.x;
  const int col = (i << 2) & (DIN - 1);
  const float4 v = x[i];
  const float4 m = *(const float4*)(mean + col);
  const float4 s = *(const float4*)(stdv + col);
  ushort4 o;
  o.x = f2bf((v.x - m.x) / s.x);
  o.y = f2bf((v.y - m.y) / s.y);
  o.z = f2bf((v.z - m.z) / s.z);
  o.w = f2bf((v.w - m.w) / s.w);
  xn[i] = o;
}

// ---------------- generic f32 -> bf16 convert ----------------
__global__ __launch_bounds__(256) void k_cvt(
    const float4* __restrict__ in, ushort4* __restrict__ out) {
  const int i = blockIdx.x * 256 + threadIdx.x;
  const float4 v = in[i];
  ushort4 o;
  o.x = f2bf(v.x); o.y = f2bf(v.y); o.z = f2bf(v.z); o.w = f2bf(v.w);
  out[i] = o;
}

// ---------------- NT GEMM: out[m][n] = sum_k A[m][k]*W[n][k] + bias[n] ----------------
// EPI==0: relu + bf16 store (h).  EPI==1: f32 store (res).
// 128x128 tile, BK=64, 4 waves (each 64x64 = 4x4 frags of 16x16x32 MFMA).
template <int EPI>
__global__ __launch_bounds__(256) void k_gemm(
    const unsigned short* __restrict__ A, const unsigned short* __restrict__ W,
    const float* __restrict__ bias, void* __restrict__ outp,
    const int N, const int K, const int nbn) {
  __shared__ unsigned short As[128 * 64];
  __shared__ unsigned short Bs[128 * 64];
  const int tid = threadIdx.x;
  const int wave = tid >> 6, lane = tid & 63;
  const int wr = wave >> 1, wc = wave & 1;

  // XCD-aware bijective swizzle, valid for ANY nwg (m204 formula)
  const int nwg = (int)gridDim.x;
  const int wg = (int)blockIdx.x;
  const int q = nwg >> 3, r = nwg & 7;
  const int xcd = wg & 7, loc = wg >> 3;
  const int swz = (xcd < r ? xcd * (q + 1) : r * (q + 1) + (xcd - r) * q) + loc;
  const int bm = swz / nbn, bn = swz % nbn;
  const int R0 = bm * 128, C0 = bn * 128;

  const int ca = wave * 4;         // this wave's first 1KB chunk
  const int srow = lane >> 3;      // 0..7 row within chunk
  const int skk = (lane & 7) * 8;  // k element offset

  f32x4 acc[4][4] = {};

  for (int k0 = 0; k0 < K; k0 += 64) {
    __syncthreads();
#pragma unroll
    for (int qq = 0; qq < 4; ++qq) {
      const int c = ca + qq;
      const int row = c * 8 + srow;
      gload16(As + c * 512, A + (size_t)(R0 + row) * K + (k0 + skk));
      gload16(Bs + c * 512, W + (size_t)(C0 + row) * K + (k0 + skk));
    }
    __syncthreads();
#pragma unroll
    for (int ks = 0; ks < 2; ++ks) {
      bf16x8 af[4], bw[4];
#pragma unroll
      for (int i = 0; i < 4; ++i) {
        af[i] = *(const bf16x8*)(As + (wr * 64 + i * 16 + (lane & 15)) * 64 +
                                 ks * 32 + (lane >> 4) * 8);
        bw[i] = *(const bf16x8*)(Bs + (wc * 64 + i * 16 + (lane & 15)) * 64 +
                                 ks * 32 + (lane >> 4) * 8);
      }
#pragma unroll
      for (int i = 0; i < 4; ++i)
#pragma unroll
        for (int j = 0; j < 4; ++j)
          acc[i][j] = __builtin_amdgcn_mfma_f32_16x16x32_bf16(af[i], bw[j],
                                                              acc[i][j], 0, 0, 0);
    }
  }

  // epilogue: D row = (lane>>4)*4 + r, col = lane&15
  const int m0 = wr * 64 + ((lane >> 4) << 2) + R0;
  const int n0 = C0 + wc * 64 + (lane & 15);
#pragma unroll
  for (int j = 0; j < 4; ++j) {
    const int n = n0 + j * 16;
    const float bv = bias[n];
#pragma unroll
    for (int i = 0; i < 4; ++i) {
#pragma unroll
      for (int r = 0; r < 4; ++r) {
        const int m = m0 + i * 16 + r;
        float v = acc[i][j][r] + bv;
        if (EPI == 0) {
          v = fmaxf(v, 0.0f);
          ((unsigned short*)outp)[(size_t)m * N + n] = f2bf(v);
        } else {
          ((float*)outp)[(size_t)m * N + n] = v;
        }
      }
    }
  }
}

// ---------------- finalize (in-place on res==out): clip, affine, +x, row-normalize ----------------
__global__ __launch_bounds__(256) void k_finalize(
    float* __restrict__ res, const float* __restrict__ x,
    const float* __restrict__ out_mean, const float* __restrict__ out_std,
    const float* __restrict__ in_mean, const int* __restrict__ nmp) {
  const int wave = threadIdx.x >> 6, lane = threadIdx.x & 63;
  const size_t row = (size_t)blockIdx.x * 4 + wave;
  const float nm = (float)(*nmp);
  const size_t base = row * DOUT + (size_t)lane * 8;
  const int c = lane * 8;
  const float4 r0 = *(const float4*)(res + base);
  const float4 r1 = *(const float4*)(res + base + 4);
  float ss = r0.x * r0.x + r0.y * r0.y + r0.z * r0.z + r0.w * r0.w +
             r1.x * r1.x + r1.y * r1.y + r1.z * r1.z + r1.w * r1.w;
#pragma unroll
  for (int o = 32; o > 0; o >>= 1) ss += __shfl_xor(ss, o);
  const float rn = sqrtf(ss);
  const float sc = (rn > nm) ? (nm / rn) : 1.0f;
  const float4 os0 = *(const float4*)(out_std + c);
  const float4 os1 = *(const float4*)(out_std + c + 4);
  const float4 om0 = *(const float4*)(out_mean + c);
  const float4 om1 = *(const float4*)(out_mean + c + 4);
  const float4 im0 = *(const float4*)(in_mean + c);
  const float4 im1 = *(const float4*)(in_mean + c + 4);
  const float4 x0 = *(const float4*)(x + base);
  const float4 x1 = *(const float4*)(x + base + 4);
  float4 m0, m1;
  m0.x = r0.x * sc * os0.x + om0.x - im0.x + x0.x;
  m0.y = r0.y * sc * os0.y + om0.y - im0.y + x0.y;
  m0.z = r0.z * sc * os0.z + om0.z - im0.z + x0.z;
  m0.w = r0.w * sc * os0.w + om0.w - im0.w + x0.w;
  m1.x = r1.x * sc * os1.x + om1.x - im1.x + x1.x;
  m1.y = r1.y * sc * os1.y + om1.y - im1.y + x1.y;
  m1.z = r1.z * sc * os1.z + om1.z - im1.z + x1.z;
  m1.w = r1.w * sc * os1.w + om1.w - im1.w + x1.w;
  float s2 = m0.x * m0.x + m0.y * m0.y + m0.z * m0.z + m0.w * m0.w +
             m1.x * m1.x + m1.y * m1.y + m1.z * m1.z + m1.w * m1.w;
#pragma unroll
  for (int o = 32; o > 0; o >>= 1) s2 += __shfl_xor(s2, o);
  const float inv = 1.0f / fmaxf(sqrtf(s2), 1e-12f);
  float4 o0, o1;
  o0.x = m0.x * inv; o0.y = m0.y * inv; o0.z = m0.z * inv; o0.w = m0.w * inv;
  o1.x = m1.x * inv; o1.y = m1.y * inv; o1.z = m1.z * inv; o1.w = m1.w * inv;
  *(float4*)(res + base) = o0;
  *(float4*)(res + base + 4) = o1;
}

extern "C" void kernel_launch(void* const* d_in, const int* in_sizes, int n_in,
                              void* d_out, int out_size, void* d_ws, size_t ws_size,
                              hipStream_t stream) {
  const float* x = (const float*)d_in[0];
  const float* in_mean = (const float*)d_in[1];
  const float* in_std = (const float*)d_in[2];
  const float* out_mean = (const float*)d_in[3];
  const float* out_std = (const float*)d_in[4];
  const float* W1 = (const float*)d_in[5];
  const float* b1 = (const float*)d_in[6];
  const float* W2 = (const float*)d_in[7];
  const float* b2 = (const float*)d_in[8];
  const int* nmp = (const int*)d_in[9];
  float* out = (float*)d_out;

  // ---- workspace layout (adaptive: h holds only `chunk` batch rows) ----
  char* ws = (char*)d_ws;
  unsigned short* xn = (unsigned short*)ws;   ws += (size_t)NB * DIN * 2;    // 32 MB
  unsigned short* W1b = (unsigned short*)ws;  ws += (size_t)DHID * DIN * 2;  //  4 MB
  unsigned short* W2b = (unsigned short*)ws;  ws += (size_t)DOUT * DHID * 2; //  4 MB
  unsigned short* h = (unsigned short*)ws;    // chunk * DHID bf16

  const size_t fixedB = (size_t)(ws - (char*)d_ws);
  const size_t avail = (ws_size > fixedB) ? (ws_size - fixedB) : 0;
  long long crows = (long long)(avail / ((size_t)DHID * 2));
  if (crows > NB) crows = NB;
  crows &= ~127LL;                 // multiple of 128
  if (crows < 128) crows = 128;    // last resort (would need >=41 MB ws anyway)
  const int chunk = (int)crows;

  // 1) xn = bf16((x - in_mean)/in_std)
  k_prep_x<<<16384, 256, 0, stream>>>((const float4*)x, in_mean, in_std,
                                      (ushort4*)xn);
  // 2) W1, W2 -> bf16
  k_cvt<<<2048, 256, 0, stream>>>((const float4*)W1, (ushort4*)W1b);
  k_cvt<<<2048, 256, 0, stream>>>((const float4*)W2, (ushort4*)W2b);

  // 3) per-chunk: h = relu(xn@W1^T + b1); res(=d_out) = h@W2^T + b2
  for (int s = 0; s < NB; s += chunk) {
    const int mc = (NB - s < chunk) ? (NB - s) : chunk;
    const int g1 = (mc / 128) * (DHID / 128);
    k_gemm<0><<<g1, 256, 0, stream>>>(xn + (size_t)s * DIN, W1b, b1, (void*)h,
                                      DHID, DIN, DHID / 128);
    const int g2 = (mc / 128) * (DOUT / 128);
    k_gemm<1><<<g2, 256, 0, stream>>>(h, W2b, b2, (void*)(out + (size_t)s * DOUT),
                                      DOUT, DHID, DOUT / 128);
  }

  // 4) finalize in-place on d_out
  k_finalize<<<NB / 4, 256, 0, stream>>>(out, x, out_mean, out_std, in_mean, nmp);
}

// Round 3
// 467.963 us; speedup vs baseline: 1.3654x; 1.3654x over previous
//
#include <hip/hip_runtime.h>
#include <hip/hip_bf16.h>

#define NB 32768
#define DIN 512
#define DHID 4096
#define DOUT 512

typedef __attribute__((ext_vector_type(8))) __bf16 bf16x8;
typedef __attribute__((ext_vector_type(4))) float f32x4;

__device__ __forceinline__ unsigned short f2bf(float f) {
  unsigned u = __builtin_bit_cast(unsigned, f);
  u += 0x7FFFu + ((u >> 16) & 1u);
  return (unsigned short)(u >> 16);
}

__device__ __forceinline__ void gload16(void* lds, const void* g) {
  __builtin_amdgcn_global_load_lds(
      (const __attribute__((address_space(1))) void*)g,
      (__attribute__((address_space(3))) void*)lds, 16, 0, 0);
}

// ---------------- prep: xn = bf16((x - mean)/std) ----------------
__global__ __launch_bounds__(256) void k_prep_x(
    const float4* __restrict__ x, const float* __restrict__ mean,
    const float* __restrict__ stdv, ushort4* __restrict__ xn) {
  const int i = blockIdx.x * 256 + threadIdx.x;
  const int col = (i << 2) & (DIN - 1);
  const float4 v = x[i];
  const float4 m = *(const float4*)(mean + col);
  const float4 s = *(const float4*)(stdv + col);
  ushort4 o;
  o.x = f2bf((v.x - m.x) / s.x);
  o.y = f2bf((v.y - m.y) / s.y);
  o.z = f2bf((v.z - m.z) / s.z);
  o.w = f2bf((v.w - m.w) / s.w);
  xn[i] = o;
}

// ---------------- generic f32 -> bf16 convert ----------------
__global__ __launch_bounds__(256) void k_cvt(
    const float4* __restrict__ in, ushort4* __restrict__ out) {
  const int i = blockIdx.x * 256 + threadIdx.x;
  const float4 v = in[i];
  ushort4 o;
  o.x = f2bf(v.x); o.y = f2bf(v.y); o.z = f2bf(v.z); o.w = f2bf(v.w);
  out[i] = o;
}

// ---------------- NT GEMM, pipelined: out[m][n] = sum_k A[m][k]*W[n][k] + bias[n]
// Tile 256(M) x 128(N) x 64(K). 512 threads = 8 waves (4x2), 64x64 per wave.
// 3-slot LDS ring (48 KB/slot): compute slot t%3, stage t+2 -> (t+2)%3.
// Counted s_waitcnt vmcnt(6) + raw s_barrier (loads stay in flight across
// barriers). XOR swizzle byte^=((row&7)<<4) on both sides (linear LDS dest,
// pre-swizzled global src per lane; swizzled ds_read).
// EPI==0: relu + bf16 store (h).  EPI==1: f32 store (res).
template <int EPI>
__global__ __launch_bounds__(512, 2) void k_gemm(
    const unsigned short* __restrict__ A, const unsigned short* __restrict__ W,
    const float* __restrict__ bias, void* __restrict__ outp,
    const int N, const int K, const int nbn) {
  __shared__ __align__(16) char lds[3 * 49152];
  const int tid = threadIdx.x;
  const int wave = tid >> 6, lane = tid & 63;
  const int wm = wave >> 1, wn = wave & 1;  // 4x2 wave grid
  const int lidlo = lane & 15, lidhi = lane >> 4;

  // XCD-aware bijective swizzle (m204), valid for any nwg
  const int nwg = (int)gridDim.x;
  const int wg = (int)blockIdx.x;
  const int q = nwg >> 3, r = nwg & 7;
  const int xcd = wg & 7, loc = wg >> 3;
  const int swz = (xcd < r ? xcd * (q + 1) : r * (q + 1) + (xcd - r) * q) + loc;
  const int bm = swz / nbn, bn = swz % nbn;
  const int R0 = bm * 256, C0 = bn * 128;

  const int NT = K >> 6;
  const int dbase0 = wave * 1024;

  auto STAGE = [&](int t, int s) {
    char* as = lds + s * 49152;
    char* bs = as + 32768;
    const int k0 = t << 6;
#pragma unroll
    for (int i = 0; i < 4; ++i) {
      const int db = i * 8192 + dbase0;
      const int d = db + lane * 16;
      const int row = d >> 7;
      const int colb = (d & 127) ^ ((row & 7) << 4);
      gload16(as + db,
              (const char*)A + ((size_t)(R0 + row) * K + k0) * 2 + colb);
    }
#pragma unroll
    for (int i = 0; i < 2; ++i) {
      const int db = i * 8192 + dbase0;
      const int d = db + lane * 16;
      const int row = d >> 7;
      const int colb = (d & 127) ^ ((row & 7) << 4);
      gload16(bs + db,
              (const char*)W + ((size_t)(C0 + row) * K + k0) * 2 + colb);
    }
  };

  f32x4 acc[4][4] = {};

  STAGE(0, 0);
  STAGE(1, 1);
  asm volatile("s_waitcnt vmcnt(6)" ::: "memory");  // tile 0 landed
  __builtin_amdgcn_s_barrier();

  int slot = 0;
  for (int t = 0; t < NT; ++t) {
    const int nslot = (slot == 2) ? 0 : slot + 1;
    const int sslot = (nslot == 2) ? 0 : nslot + 1;
    if (t + 2 < NT) STAGE(t + 2, sslot);

    const char* as = lds + slot * 49152;
    const char* bs = as + 32768;
    bf16x8 af[2][4], bw[2][4];
#pragma unroll
    for (int kk = 0; kk < 2; ++kk) {
#pragma unroll
      for (int i = 0; i < 4; ++i) {
        const int ra = wm * 64 + i * 16 + lidlo;
        af[kk][i] = *(const bf16x8*)(
            as + ra * 128 + ((kk * 64 + lidhi * 16) ^ ((ra & 7) << 4)));
        const int rb = wn * 64 + i * 16 + lidlo;
        bw[kk][i] = *(const bf16x8*)(
            bs + rb * 128 + ((kk * 64 + lidhi * 16) ^ ((rb & 7) << 4)));
      }
    }
    __builtin_amdgcn_s_setprio(1);
#pragma unroll
    for (int kk = 0; kk < 2; ++kk)
#pragma unroll
      for (int i = 0; i < 4; ++i)
#pragma unroll
        for (int j = 0; j < 4; ++j)
          acc[i][j] = __builtin_amdgcn_mfma_f32_16x16x32_bf16(
              af[kk][i], bw[kk][j], acc[i][j], 0, 0, 0);
    __builtin_amdgcn_s_setprio(0);

    if (t + 2 < NT) {
      asm volatile("s_waitcnt vmcnt(6)" ::: "memory");  // tile t+1 landed
    } else {
      asm volatile("s_waitcnt vmcnt(0)" ::: "memory");  // tail drain
    }
    __builtin_amdgcn_s_barrier();
    slot = nslot;
  }

  // epilogue: D row = (lane>>4)*4 + r, col = lane&15 (verified mapping)
  const int m0 = R0 + wm * 64 + (lidhi << 2);
  const int n0 = C0 + wn * 64 + lidlo;
#pragma unroll
  for (int j = 0; j < 4; ++j) {
    const int n = n0 + j * 16;
    const float bv = bias[n];
#pragma unroll
    for (int i = 0; i < 4; ++i) {
#pragma unroll
      for (int rr = 0; rr < 4; ++rr) {
        const int m = m0 + i * 16 + rr;
        float v = acc[i][j][rr] + bv;
        if (EPI == 0) {
          v = fmaxf(v, 0.0f);
          ((unsigned short*)outp)[(size_t)m * N + n] = f2bf(v);
        } else {
          ((float*)outp)[(size_t)m * N + n] = v;
        }
      }
    }
  }
}

// ---------------- finalize (in-place on res==out): clip, affine, +x, row-normalize ----------------
__global__ __launch_bounds__(256) void k_finalize(
    float* __restrict__ res, const float* __restrict__ x,
    const float* __restrict__ out_mean, const float* __restrict__ out_std,
    const float* __restrict__ in_mean, const int* __restrict__ nmp) {
  const int wave = threadIdx.x >> 6, lane = threadIdx.x & 63;
  const size_t row = (size_t)blockIdx.x * 4 + wave;
  const float nm = (float)(*nmp);
  const size_t base = row * DOUT + (size_t)lane * 8;
  const int c = lane * 8;
  const float4 r0 = *(const float4*)(res + base);
  const float4 r1 = *(const float4*)(res + base + 4);
  float ss = r0.x * r0.x + r0.y * r0.y + r0.z * r0.z + r0.w * r0.w +
             r1.x * r1.x + r1.y * r1.y + r1.z * r1.z + r1.w * r1.w;
#pragma unroll
  for (int o = 32; o > 0; o >>= 1) ss += __shfl_xor(ss, o);
  const float rn = sqrtf(ss);
  const float sc = (rn > nm) ? (nm / rn) : 1.0f;
  const float4 os0 = *(const float4*)(out_std + c);
  const float4 os1 = *(const float4*)(out_std + c + 4);
  const float4 om0 = *(const float4*)(out_mean + c);
  const float4 om1 = *(const float4*)(out_mean + c + 4);
  const float4 im0 = *(const float4*)(in_mean + c);
  const float4 im1 = *(const float4*)(in_mean + c + 4);
  const float4 x0 = *(const float4*)(x + base);
  const float4 x1 = *(const float4*)(x + base + 4);
  float4 m0, m1;
  m0.x = r0.x * sc * os0.x + om0.x - im0.x + x0.x;
  m0.y = r0.y * sc * os0.y + om0.y - im0.y + x0.y;
  m0.z = r0.z * sc * os0.z + om0.z - im0.z + x0.z;
  m0.w = r0.w * sc * os0.w + om0.w - im0.w + x0.w;
  m1.x = r1.x * sc * os1.x + om1.x - im1.x + x1.x;
  m1.y = r1.y * sc * os1.y + om1.y - im1.y + x1.y;
  m1.z = r1.z * sc * os1.z + om1.z - im1.z + x1.z;
  m1.w = r1.w * sc * os1.w + om1.w - im1.w + x1.w;
  float s2 = m0.x * m0.x + m0.y * m0.y + m0.z * m0.z + m0.w * m0.w +
             m1.x * m1.x + m1.y * m1.y + m1.z * m1.z + m1.w * m1.w;
#pragma unroll
  for (int o = 32; o > 0; o >>= 1) s2 += __shfl_xor(s2, o);
  const float inv = 1.0f / fmaxf(sqrtf(s2), 1e-12f);
  float4 o0, o1;
  o0.x = m0.x * inv; o0.y = m0.y * inv; o0.z = m0.z * inv; o0.w = m0.w * inv;
  o1.x = m1.x * inv; o1.y = m1.y * inv; o1.z = m1.z * inv; o1.w = m1.w * inv;
  *(float4*)(res + base) = o0;
  *(float4*)(res + base + 4) = o1;
}

extern "C" void kernel_launch(void* const* d_in, const int* in_sizes, int n_in,
                              void* d_out, int out_size, void* d_ws, size_t ws_size,
                              hipStream_t stream) {
  const float* x = (const float*)d_in[0];
  const float* in_mean = (const float*)d_in[1];
  const float* in_std = (const float*)d_in[2];
  const float* out_mean = (const float*)d_in[3];
  const float* out_std = (const float*)d_in[4];
  const float* W1 = (const float*)d_in[5];
  const float* b1 = (const float*)d_in[6];
  const float* W2 = (const float*)d_in[7];
  const float* b2 = (const float*)d_in[8];
  const int* nmp = (const int*)d_in[9];
  float* out = (float*)d_out;

  // ---- workspace layout (adaptive: h holds only `chunk` batch rows) ----
  char* ws = (char*)d_ws;
  unsigned short* xn = (unsigned short*)ws;   ws += (size_t)NB * DIN * 2;    // 32 MB
  unsigned short* W1b = (unsigned short*)ws;  ws += (size_t)DHID * DIN * 2;  //  4 MB
  unsigned short* W2b = (unsigned short*)ws;  ws += (size_t)DOUT * DHID * 2; //  4 MB
  unsigned short* h = (unsigned short*)ws;    // chunk * DHID bf16

  const size_t fixedB = (size_t)(ws - (char*)d_ws);
  const size_t avail = (ws_size > fixedB) ? (ws_size - fixedB) : 0;
  long long crows = (long long)(avail / ((size_t)DHID * 2));
  if (crows > NB) crows = NB;
  crows &= ~255LL;                 // multiple of 256 (BM)
  if (crows < 256) crows = 256;
  const int chunk = (int)crows;

  // 1) xn = bf16((x - in_mean)/in_std)
  k_prep_x<<<16384, 256, 0, stream>>>((const float4*)x, in_mean, in_std,
                                      (ushort4*)xn);
  // 2) W1, W2 -> bf16
  k_cvt<<<2048, 256, 0, stream>>>((const float4*)W1, (ushort4*)W1b);
  k_cvt<<<2048, 256, 0, stream>>>((const float4*)W2, (ushort4*)W2b);

  // 3) per-chunk: h = relu(xn@W1^T + b1); res(=d_out) = h@W2^T + b2
  for (int s = 0; s < NB; s += chunk) {
    const int mc = (NB - s < chunk) ? (NB - s) : chunk;
    const int g1 = (mc / 256) * (DHID / 128);
    k_gemm<0><<<g1, 512, 0, stream>>>(xn + (size_t)s * DIN, W1b, b1, (void*)h,
                                      DHID, DIN, DHID / 128);
    const int g2 = (mc / 256) * (DOUT / 128);
    k_gemm<1><<<g2, 512, 0, stream>>>(h, W2b, b2, (void*)(out + (size_t)s * DOUT),
                                      DOUT, DHID, DOUT / 128);
  }

  // 4) finalize in-place on d_out
  k_finalize<<<NB / 4, 256, 0, stream>>>(out, x, out_mean, out_std, in_mean, nmp);
}